// Round 1
// baseline (296.350 us; speedup 1.0000x reference)
//
#include <hip/hip_runtime.h>
#include <cstddef>

constexpr int CB  = 2;      // batch
constexpr int CH  = 16;     // heads
constexpr int CS  = 4096;   // sequence
constexpr int CD  = 64;     // head dim
constexpr int CG  = 64;     // max_global (static per reference)
constexpr int CBH = CB * CH;
constexpr int NCH = 32;     // key chunks for global part
constexpr int CHK = 128;    // keys per chunk (NCH*CHK == CS)

__device__ __forceinline__ float dot4(float acc, float4 a, float4 b) {
  acc = fmaf(a.x, b.x, acc);
  acc = fmaf(a.y, b.y, acc);
  acc = fmaf(a.z, b.z, acc);
  acc = fmaf(a.w, b.w, acc);
  return acc;
}

__device__ __forceinline__ void fma4(float4& a, float s, float4 b) {
  a.x = fmaf(s, b.x, a.x);
  a.y = fmaf(s, b.y, a.y);
  a.z = fmaf(s, b.z, a.z);
  a.w = fmaf(s, b.w, a.w);
}

// ---------------------------------------------------------------------------
// Build compacted global-token position table per batch: gpos[b][g], gcount[b]
// 64 threads per batch row; prefix-scan over per-thread counts.
// ---------------------------------------------------------------------------
__global__ void k_setup(const int* __restrict__ mask,
                        int* __restrict__ gpos, int* __restrict__ gcount) {
  const int b = blockIdx.x;
  const int t = threadIdx.x;  // 64 threads
  __shared__ int cnt[64];
  if (t < CG) gpos[b * CG + t] = 0;  // safe default index for unused slots
  const int span = CS / 64;
  const int base = b * CS + t * span;
  int c = 0;
  for (int i = 0; i < span; ++i) c += (mask[base + i] > 0) ? 1 : 0;
  cnt[t] = c;
  __syncthreads();
  int pre = 0;
  for (int j = 0; j < t; ++j) pre += cnt[j];
  for (int i = 0; i < span; ++i) {
    if (mask[base + i] > 0) {
      if (pre < CG) gpos[b * CG + pre] = t * span + i;
      ++pre;
    }
  }
  if (t == 63) gcount[b] = (pre < CG) ? pre : CG;
}

// ---------------------------------------------------------------------------
// Part 1: every query row attends to the G compacted global KVs.
// Thread-per-row, gK/gV staged in LDS (float4, broadcast reads).
// Online softmax over 8-g chunks; writes RAW scores to probs (k_norm fixes),
// per-row m,l to ws, and normalized part-1 context.
// ---------------------------------------------------------------------------
__global__ __launch_bounds__(256) void k_local(
    const float* __restrict__ q, const float* __restrict__ k,
    const float* __restrict__ v,
    const int* __restrict__ gpos, const int* __restrict__ gcount,
    float* __restrict__ ctx, float* __restrict__ probs,
    float* __restrict__ mbuf, float* __restrict__ lbuf) {
  __shared__ float4 gk4[CG][CD / 4];
  __shared__ float4 gv4[CG][CD / 4];
  __shared__ int gp[CG];
  __shared__ int gcs_s;
  const int bh = blockIdx.y;
  const int b = bh / CH;
  const int t = threadIdx.x;
  if (t < CG) gp[t] = gpos[b * CG + t];
  if (t == 0) gcs_s = gcount[b];
  __syncthreads();
  for (int idx = t; idx < CG * (CD / 4); idx += 256) {
    const int g = idx >> 4, dj = idx & 15;
    const size_t off = ((size_t)(bh * CS + gp[g])) * CD + dj * 4;
    gk4[g][dj] = *(const float4*)(k + off);
    gv4[g][dj] = *(const float4*)(v + off);
  }
  __syncthreads();
  const int gc = gcs_s;
  const int row = blockIdx.x * 256 + t;
  const float* qr = q + ((size_t)(bh * CS + row)) * CD;
  float4 q4[16];
#pragma unroll
  for (int dj = 0; dj < 16; ++dj) {
    float4 x = *(const float4*)(qr + dj * 4);
    x.x *= 0.125f; x.y *= 0.125f; x.z *= 0.125f; x.w *= 0.125f;  // 1/sqrt(64)
    q4[dj] = x;
  }
  float4 c4[16];
#pragma unroll
  for (int dj = 0; dj < 16; ++dj) c4[dj] = make_float4(0.f, 0.f, 0.f, 0.f);
  float m = -1e30f, l = 0.f;
  float* prow = probs + ((size_t)(bh * CS + row)) * CG;
  for (int cc = 0; cc < CG / 8; ++cc) {
    float sc[8];
#pragma unroll
    for (int j = 0; j < 8; ++j) {
      const int g = cc * 8 + j;
      float a = 0.f;
#pragma unroll
      for (int dj = 0; dj < 16; ++dj) a = dot4(a, q4[dj], gk4[g][dj]);
      sc[j] = (g < gc) ? a : -1e30f;
    }
    *(float4*)(prow + cc * 8)     = make_float4(sc[0], sc[1], sc[2], sc[3]);
    *(float4*)(prow + cc * 8 + 4) = make_float4(sc[4], sc[5], sc[6], sc[7]);
    float cmax = sc[0];
#pragma unroll
    for (int j = 1; j < 8; ++j) cmax = fmaxf(cmax, sc[j]);
    const float mnew = fmaxf(m, cmax);
    const float scale = __expf(m - mnew);  // first chunk: exp(-1e30-x)=0
    l *= scale;
#pragma unroll
    for (int dj = 0; dj < 16; ++dj) {
      c4[dj].x *= scale; c4[dj].y *= scale; c4[dj].z *= scale; c4[dj].w *= scale;
    }
#pragma unroll
    for (int j = 0; j < 8; ++j) {
      const int g = cc * 8 + j;
      const float p = __expf(sc[j] - mnew);
      l += p;
#pragma unroll
      for (int dj = 0; dj < 16; ++dj) fma4(c4[dj], p, gv4[g][dj]);
    }
    m = mnew;
  }
  mbuf[(size_t)bh * CS + row] = m;
  lbuf[(size_t)bh * CS + row] = l;
  const float inv = 1.0f / l;
  float* crow = ctx + ((size_t)(bh * CS + row)) * CD;
#pragma unroll
  for (int dj = 0; dj < 16; ++dj) {
    float4 o = c4[dj];
    o.x *= inv; o.y *= inv; o.z *= inv; o.w *= inv;
    *(float4*)(crow + dj * 4) = o;
  }
}

// ---------------------------------------------------------------------------
// Normalize raw scores -> probs, fully coalesced float4 pass.
// ---------------------------------------------------------------------------
__global__ __launch_bounds__(256) void k_norm(
    float* __restrict__ probs, const float* __restrict__ mbuf,
    const float* __restrict__ lbuf) {
  const size_t i4 = ((size_t)blockIdx.x * 256 + threadIdx.x) * 4;
  const size_t r = i4 >> 6;  // CG == 64
  const float m = mbuf[r];
  const float inv = 1.0f / lbuf[r];
  float4 x = *(float4*)(probs + i4);
  x.x = __expf(x.x - m) * inv;
  x.y = __expf(x.y - m) * inv;
  x.z = __expf(x.z - m) * inv;
  x.w = __expf(x.w - m) * inv;
  *(float4*)(probs + i4) = x;
}

// ---------------------------------------------------------------------------
// Part 2 (partial): global queries do full attention. One block per
// (key-chunk, bh). Scores in LDS (stride 129 -> conflict-free), partial
// softmax stats + partial PV written to workspace.
// ---------------------------------------------------------------------------
__global__ __launch_bounds__(256) void k_gpart(
    const float* __restrict__ q, const float* __restrict__ k,
    const float* __restrict__ v,
    const int* __restrict__ gpos, const int* __restrict__ gcount,
    float* __restrict__ pm, float* __restrict__ pl, float* __restrict__ pctx) {
  __shared__ float scl[CG][CHK + 1];
  __shared__ int gp[CG];
  const int chunk = blockIdx.x;
  const int bh = blockIdx.y;
  const int b = bh / CH;
  const int t = threadIdx.x;
  if (t < CG) gp[t] = gpos[b * CG + t];
  __syncthreads();
  const int g = t & 63;   // this thread's query slot
  const int wv = t >> 6;  // wave id 0..3
  const float* qr = q + ((size_t)(bh * CS + gp[g])) * CD;
  float4 q4[16];
#pragma unroll
  for (int dj = 0; dj < 16; ++dj) {
    float4 x = *(const float4*)(qr + dj * 4);
    x.x *= 0.125f; x.y *= 0.125f; x.z *= 0.125f; x.w *= 0.125f;
    q4[dj] = x;
  }
  const int base = chunk * CHK;
  for (int i = 0; i < CHK / 4; ++i) {
    const int sl = wv * (CHK / 4) + i;  // wave-uniform key row -> broadcast loads
    const float* kr = k + ((size_t)(bh * CS + base + sl)) * CD;
    float a = 0.f;
#pragma unroll
    for (int dj = 0; dj < 16; ++dj) a = dot4(a, q4[dj], *(const float4*)(kr + dj * 4));
    scl[g][sl] = a;
  }
  __syncthreads();
  if (t < CG) {
    float mm = -1e30f;
    for (int i = 0; i < CHK; ++i) mm = fmaxf(mm, scl[t][i]);
    float ll = 0.f;
    for (int i = 0; i < CHK; ++i) {
      const float p = __expf(scl[t][i] - mm);
      scl[t][i] = p;
      ll += p;
    }
    const size_t o = ((size_t)(bh * NCH + chunk)) * CG + t;
    pm[o] = mm;
    pl[o] = ll;
  }
  __syncthreads();
  float4 acc[4];
#pragma unroll
  for (int j = 0; j < 4; ++j) acc[j] = make_float4(0.f, 0.f, 0.f, 0.f);
  for (int i = 0; i < CHK; ++i) {
    const float p = scl[g][i];
    const float* vr = v + ((size_t)(bh * CS + base + i)) * CD + wv * 16;
#pragma unroll
    for (int j = 0; j < 4; ++j) fma4(acc[j], p, *(const float4*)(vr + j * 4));
  }
  float* po = pctx + (((size_t)(bh * NCH + chunk)) * CG + g) * CD + wv * 16;
#pragma unroll
  for (int j = 0; j < 4; ++j) *(float4*)(po + j * 4) = acc[j];
}

// ---------------------------------------------------------------------------
// Merge NCH partials per (bh,g) and scatter into context at token position.
// Must run after k_local (stream-ordered) since it overwrites those rows.
// ---------------------------------------------------------------------------
__global__ __launch_bounds__(64) void k_combine(
    const float* __restrict__ pm, const float* __restrict__ pl,
    const float* __restrict__ pctx,
    const int* __restrict__ gpos, const int* __restrict__ gcount,
    float* __restrict__ ctx) {
  const int g = blockIdx.x;
  const int bh = blockIdx.y;
  const int b = bh / CH;
  if (g >= gcount[b]) return;
  const int d = threadIdx.x;
  float m = -1e30f;
  for (int c = 0; c < NCH; ++c)
    m = fmaxf(m, pm[((size_t)(bh * NCH + c)) * CG + g]);
  float L = 0.f, acc = 0.f;
  for (int c = 0; c < NCH; ++c) {
    const size_t o = ((size_t)(bh * NCH + c)) * CG + g;
    const float w = __expf(pm[o] - m);
    L = fmaf(w, pl[o], L);
    acc = fmaf(w, pctx[o * CD + d], acc);
  }
  const int tok = gpos[b * CG + g];
  ctx[((size_t)(bh * CS + tok)) * CD + d] = acc / L;
}

extern "C" void kernel_launch(void* const* d_in, const int* in_sizes, int n_in,
                              void* d_out, int out_size, void* d_ws, size_t ws_size,
                              hipStream_t stream) {
  const float* q = (const float*)d_in[0];
  const float* k = (const float*)d_in[1];
  const float* v = (const float*)d_in[2];
  const int* mask = (const int*)d_in[3];
  // d_in[4] = max_global (static CG=64), unused

  float* ctx = (float*)d_out;                        // B*H*S*D
  float* probs = ctx + (size_t)CBH * CS * CD;        // B*H*S*G

  char* ws = (char*)d_ws;
  int* gpos = (int*)ws;                              // CB*CG ints (<=512B)
  int* gcount = (int*)(ws + 512);                    // CB ints
  float* mbuf = (float*)(ws + 1024);                 // CBH*CS
  float* lbuf = mbuf + (size_t)CBH * CS;             // CBH*CS
  float* pm = lbuf + (size_t)CBH * CS;               // CBH*NCH*CG
  float* pl = pm + (size_t)CBH * NCH * CG;           // CBH*NCH*CG
  float* pctx = pl + (size_t)CBH * NCH * CG;         // CBH*NCH*CG*CD (~16.8MB)

  k_setup<<<dim3(CB), dim3(64), 0, stream>>>(mask, gpos, gcount);
  k_local<<<dim3(CS / 256, CBH), dim3(256), 0, stream>>>(
      q, k, v, gpos, gcount, ctx, probs, mbuf, lbuf);
  k_norm<<<dim3((CBH * (size_t)CS * CG / 4) / 256), dim3(256), 0, stream>>>(
      probs, mbuf, lbuf);
  k_gpart<<<dim3(NCH, CBH), dim3(256), 0, stream>>>(
      q, k, v, gpos, gcount, pm, pl, pctx);
  k_combine<<<dim3(CG, CBH), dim3(64), 0, stream>>>(
      pm, pl, pctx, gpos, gcount, ctx);
}

// Round 2
// 122.511 us; speedup vs baseline: 2.4190x; 2.4190x over previous
//
#include <hip/hip_runtime.h>
#include <cstddef>

constexpr int CB  = 2;      // batch
constexpr int CH  = 16;     // heads
constexpr int CS  = 4096;   // sequence
constexpr int CD  = 64;     // head dim
constexpr int CG  = 64;     // max_global (static per reference)
constexpr int CBH = CB * CH;
constexpr int NCH = 32;     // key chunks for global part (blocks per bh)
constexpr int TK  = 64;     // keys per LDS tile in k_gpart
constexpr int TPC = 2;      // tiles per chunk (NCH*TPC*TK == CS)

__device__ __forceinline__ float dot4(float acc, float4 a, float4 b) {
  acc = fmaf(a.x, b.x, acc);
  acc = fmaf(a.y, b.y, acc);
  acc = fmaf(a.z, b.z, acc);
  acc = fmaf(a.w, b.w, acc);
  return acc;
}

__device__ __forceinline__ void fma4(float4& a, float s, float4 b) {
  a.x = fmaf(s, b.x, a.x);
  a.y = fmaf(s, b.y, a.y);
  a.z = fmaf(s, b.z, a.z);
  a.w = fmaf(s, b.w, a.w);
}

__device__ __forceinline__ void mul4(float4& a, float s) {
  a.x *= s; a.y *= s; a.z *= s; a.w *= s;
}

// DPP quad_perm helpers (VALU-speed cross-lane within each 4-lane quad)
template <int CTRL>
__device__ __forceinline__ float dppf(float x) {
  return __int_as_float(__builtin_amdgcn_update_dpp(
      0, __float_as_int(x), CTRL, 0xf, 0xf, true));
}
__device__ __forceinline__ float quad_add(float x) {
  x += dppf<0xB1>(x);  // quad_perm [1,0,3,2]
  x += dppf<0x4E>(x);  // quad_perm [2,3,0,1]
  return x;
}
template <int DD>
__device__ __forceinline__ float quad_bcast(float x) {
  return dppf<DD * 0x55>(x);  // quad_perm [DD,DD,DD,DD]
}

// ---------------------------------------------------------------------------
// Build compacted global-token position table per batch: gpos[b][g], gcount[b]
// ---------------------------------------------------------------------------
__global__ void k_setup(const int* __restrict__ mask,
                        int* __restrict__ gpos, int* __restrict__ gcount) {
  const int b = blockIdx.x;
  const int t = threadIdx.x;  // 64 threads
  __shared__ int cnt[64];
  if (t < CG) gpos[b * CG + t] = 0;  // safe default index for unused slots
  const int span = CS / 64;
  const int base = b * CS + t * span;
  int c = 0;
  for (int i = 0; i < span; ++i) c += (mask[base + i] > 0) ? 1 : 0;
  cnt[t] = c;
  __syncthreads();
  int pre = 0;
  for (int j = 0; j < t; ++j) pre += cnt[j];
  for (int i = 0; i < span; ++i) {
    if (mask[base + i] > 0) {
      if (pre < CG) gpos[b * CG + pre] = t * span + i;
      ++pre;
    }
  }
  if (t == 63) gcount[b] = (pre < CG) ? pre : CG;
}

// ---------------------------------------------------------------------------
// Part 1: every query row attends to the G compacted global KVs.
// Block = 64 rows x 4 d-quarters (256 thr). gK/gV staged in LDS coalesced.
// Scores quad-reduced via DPP; softmax finalized in-kernel (no k_norm pass).
// ---------------------------------------------------------------------------
__global__ __launch_bounds__(256) void k_local(
    const float* __restrict__ q, const float* __restrict__ k,
    const float* __restrict__ v,
    const int* __restrict__ gpos, const int* __restrict__ gcount,
    float* __restrict__ ctx, float* __restrict__ probs) {
  __shared__ __align__(16) float gk[CG][CD];
  __shared__ __align__(16) float gv[CG][CD];
  __shared__ int gp[CG];
  __shared__ int gc_s;
  const int bh = blockIdx.y;
  const int b = bh / CH;
  const int t = threadIdx.x;
  if (t < CG) gp[t] = gpos[b * CG + t];
  if (t == 0) gc_s = gcount[b];
  __syncthreads();
  // stage gathered K/V rows, coalesced float4
#pragma unroll
  for (int r = 0; r < 4; ++r) {
    const int fl = t + 256 * r;                // float4 slot 0..1023
    const int grow = fl >> 4, col = (fl & 15) * 4;
    const size_t off = ((size_t)(bh * CS + gp[grow])) * CD + col;
    *(float4*)&gk[grow][col] = *(const float4*)(k + off);
    *(float4*)&gv[grow][col] = *(const float4*)(v + off);
  }
  __syncthreads();
  const int gc = gc_s;
  const int row = blockIdx.x * 64 + (t >> 2);
  const int dq = t & 3;
  const float* qr = q + ((size_t)(bh * CS + row)) * CD + dq * 16;
  float4 q4[4];
#pragma unroll
  for (int jj = 0; jj < 4; ++jj) {
    float4 x = *(const float4*)(qr + jj * 4);
    mul4(x, 0.125f);  // 1/sqrt(64)
    q4[jj] = x;
  }
  // Phase A: all 64 scores; lane owns g in [dq*16, dq*16+16)
  float sc[16];
  float m = -1e30f;
#pragma unroll
  for (int j = 0; j < 16; ++j) {
#pragma unroll
    for (int dd = 0; dd < 4; ++dd) {
      const int g = dd * 16 + j;
      float a = 0.f;
#pragma unroll
      for (int jj = 0; jj < 4; ++jj)
        a = dot4(a, q4[jj], *(const float4*)&gk[g][dq * 16 + jj * 4]);
      float s = quad_add(a);
      s = (g < gc) ? s : -1e30f;
      m = fmaxf(m, s);
      if (dd == dq) sc[j] = s;
    }
  }
  // Phase B: softmax denominator + final probs
  float p[16];
  float lsum = 0.f;
#pragma unroll
  for (int j = 0; j < 16; ++j) {
    p[j] = __expf(sc[j] - m);
    lsum += p[j];
  }
  const float l = quad_add(lsum);
  const float inv = 1.0f / l;
#pragma unroll
  for (int j = 0; j < 16; ++j) p[j] *= inv;
  float* prow = probs + ((size_t)(bh * CS + row)) * CG + dq * 16;
#pragma unroll
  for (int jb = 0; jb < 4; ++jb)
    *(float4*)(prow + jb * 4) =
        make_float4(p[4 * jb], p[4 * jb + 1], p[4 * jb + 2], p[4 * jb + 3]);
  // PV: ctx quarter
  float4 c4[4];
#pragma unroll
  for (int jj = 0; jj < 4; ++jj) c4[jj] = make_float4(0.f, 0.f, 0.f, 0.f);
#pragma unroll
  for (int j = 0; j < 16; ++j) {
#pragma unroll
    for (int dd = 0; dd < 4; ++dd) {
      const int g = dd * 16 + j;
      const float pb = quad_bcast<0>(dd == 0 ? p[j] : 0.f) * 0.f +  // placeholder avoided below
                       0.f;
      (void)pb;
    }
  }
  // (real PV below; the loop above is removed by the compiler)
#pragma unroll
  for (int j = 0; j < 16; ++j) {
    {
      const float pb = quad_bcast<0>(p[j]);
#pragma unroll
      for (int jj = 0; jj < 4; ++jj)
        fma4(c4[jj], pb, *(const float4*)&gv[0 * 16 + j][dq * 16 + jj * 4]);
    }
    {
      const float pb = quad_bcast<1>(p[j]);
#pragma unroll
      for (int jj = 0; jj < 4; ++jj)
        fma4(c4[jj], pb, *(const float4*)&gv[1 * 16 + j][dq * 16 + jj * 4]);
    }
    {
      const float pb = quad_bcast<2>(p[j]);
#pragma unroll
      for (int jj = 0; jj < 4; ++jj)
        fma4(c4[jj], pb, *(const float4*)&gv[2 * 16 + j][dq * 16 + jj * 4]);
    }
    {
      const float pb = quad_bcast<3>(p[j]);
#pragma unroll
      for (int jj = 0; jj < 4; ++jj)
        fma4(c4[jj], pb, *(const float4*)&gv[3 * 16 + j][dq * 16 + jj * 4]);
    }
  }
  float* crow = ctx + ((size_t)(bh * CS + row)) * CD + dq * 16;
#pragma unroll
  for (int jj = 0; jj < 4; ++jj) *(float4*)(crow + jj * 4) = c4[jj];
}

// ---------------------------------------------------------------------------
// Part 2 (partial): global queries full-attend over a 128-key chunk
// (two sequential 64-key LDS tiles, online softmax carried across tiles).
// Block = 64 g-slots x 4 d-quarters. Partials to workspace.
// ---------------------------------------------------------------------------
__global__ __launch_bounds__(256) void k_gpart(
    const float* __restrict__ q, const float* __restrict__ k,
    const float* __restrict__ v,
    const int* __restrict__ gpos,
    float* __restrict__ pm, float* __restrict__ pl, float* __restrict__ pctx) {
  __shared__ __align__(16) float kl[TK][CD];
  __shared__ __align__(16) float vl[TK][CD];
  __shared__ int gp[CG];
  const int chunk = blockIdx.x;
  const int bh = blockIdx.y;
  const int b = bh / CH;
  const int t = threadIdx.x;
  if (t < CG) gp[t] = gpos[b * CG + t];
  __syncthreads();
  const int g = t >> 2;
  const int dq = t & 3;
  const float* qr = q + ((size_t)(bh * CS + gp[g])) * CD + dq * 16;
  float4 q4[4];
#pragma unroll
  for (int jj = 0; jj < 4; ++jj) {
    float4 x = *(const float4*)(qr + jj * 4);
    mul4(x, 0.125f);
    q4[jj] = x;
  }
  float m = -1e30f, l = 0.f;
  float4 c4[4];
#pragma unroll
  for (int jj = 0; jj < 4; ++jj) c4[jj] = make_float4(0.f, 0.f, 0.f, 0.f);
  for (int tile = 0; tile < TPC; ++tile) {
    const int kbase = chunk * (TPC * TK) + tile * TK;
    if (tile) __syncthreads();  // previous tile fully consumed
#pragma unroll
    for (int r = 0; r < 4; ++r) {
      const int fl = t + 256 * r;
      const int kr = fl >> 4, col = (fl & 15) * 4;
      const size_t off = ((size_t)(bh * CS + kbase + kr)) * CD + col;
      *(float4*)&kl[kr][col] = *(const float4*)(k + off);
      *(float4*)&vl[kr][col] = *(const float4*)(v + off);
    }
    __syncthreads();
#pragma unroll
    for (int j = 0; j < TK / 4; ++j) {
      float s[4];
#pragma unroll
      for (int dd = 0; dd < 4; ++dd) {
        const int key = j * 4 + dd;
        float a = 0.f;
#pragma unroll
        for (int jj = 0; jj < 4; ++jj)
          a = dot4(a, q4[jj], *(const float4*)&kl[key][dq * 16 + jj * 4]);
        s[dd] = quad_add(a);
      }
      const float cmax = fmaxf(fmaxf(s[0], s[1]), fmaxf(s[2], s[3]));
      const float mnew = fmaxf(m, cmax);
      const float scale = __expf(m - mnew);
      l *= scale;
#pragma unroll
      for (int jj = 0; jj < 4; ++jj) mul4(c4[jj], scale);
#pragma unroll
      for (int dd = 0; dd < 4; ++dd) {
        const int key = j * 4 + dd;
        const float pp = __expf(s[dd] - mnew);
        l += pp;
#pragma unroll
        for (int jj = 0; jj < 4; ++jj)
          fma4(c4[jj], pp, *(const float4*)&vl[key][dq * 16 + jj * 4]);
      }
      m = mnew;
    }
  }
  const size_t o = ((size_t)(bh * NCH + chunk)) * CG + g;
  if (dq == 0) {
    pm[o] = m;
    pl[o] = l;
  }
  float* po = pctx + o * CD + dq * 16;
#pragma unroll
  for (int jj = 0; jj < 4; ++jj) *(float4*)(po + jj * 4) = c4[jj];
}

// ---------------------------------------------------------------------------
// Merge NCH partials per (bh,g) and scatter into context at token position.
// ---------------------------------------------------------------------------
__global__ __launch_bounds__(64) void k_combine(
    const float* __restrict__ pm, const float* __restrict__ pl,
    const float* __restrict__ pctx,
    const int* __restrict__ gpos, const int* __restrict__ gcount,
    float* __restrict__ ctx) {
  const int g = blockIdx.x;
  const int bh = blockIdx.y;
  const int b = bh / CH;
  if (g >= gcount[b]) return;
  const int d = threadIdx.x;
  float m = -1e30f;
  for (int c = 0; c < NCH; ++c)
    m = fmaxf(m, pm[((size_t)(bh * NCH + c)) * CG + g]);
  float L = 0.f, acc = 0.f;
  for (int c = 0; c < NCH; ++c) {
    const size_t o = ((size_t)(bh * NCH + c)) * CG + g;
    const float w = __expf(pm[o] - m);
    L = fmaf(w, pl[o], L);
    acc = fmaf(w, pctx[o * CD + d], acc);
  }
  const int tok = gpos[b * CG + g];
  ctx[((size_t)(bh * CS + tok)) * CD + d] = acc / L;
}

extern "C" void kernel_launch(void* const* d_in, const int* in_sizes, int n_in,
                              void* d_out, int out_size, void* d_ws, size_t ws_size,
                              hipStream_t stream) {
  const float* q = (const float*)d_in[0];
  const float* k = (const float*)d_in[1];
  const float* v = (const float*)d_in[2];
  const int* mask = (const int*)d_in[3];
  // d_in[4] = max_global (static CG=64), unused

  float* ctx = (float*)d_out;                        // B*H*S*D
  float* probs = ctx + (size_t)CBH * CS * CD;        // B*H*S*G

  char* ws = (char*)d_ws;
  int* gpos = (int*)ws;                              // CB*CG ints
  int* gcount = (int*)(ws + 512);                    // CB ints
  float* pm = (float*)(ws + 1024);                   // CBH*NCH*CG
  float* pl = pm + (size_t)CBH * NCH * CG;           // CBH*NCH*CG
  float* pctx = pl + (size_t)CBH * NCH * CG;         // CBH*NCH*CG*CD (~16.8MB)

  k_setup<<<dim3(CB), dim3(64), 0, stream>>>(mask, gpos, gcount);
  k_local<<<dim3(CS / 64, CBH), dim3(256), 0, stream>>>(
      q, k, v, gpos, gcount, ctx, probs);
  k_gpart<<<dim3(NCH, CBH), dim3(256), 0, stream>>>(
      q, k, v, gpos, pm, pl, pctx);
  k_combine<<<dim3(CG, CBH), dim3(64), 0, stream>>>(
      pm, pl, pctx, gpos, gcount, ctx);
}

// Round 5
// 79.622 us; speedup vs baseline: 3.7219x; 1.5387x over previous
//
#include <hip/hip_runtime.h>
#include <cstddef>

constexpr int CB  = 2;
constexpr int CH  = 16;
constexpr int CS  = 4096;
constexpr int CD  = 64;
constexpr int CG  = 64;
constexpr int CBH = CB * CH;
constexpr int G2NCH = 32;        // part-2 blocks per bh (128-key window each)
constexpr int NPART = G2NCH * 2; // partials per (bh,q): block x key-half

typedef float  f32x16 __attribute__((ext_vector_type(16)));
typedef short  short8 __attribute__((ext_vector_type(8)));
typedef float  fvec4  __attribute__((ext_vector_type(4)));

union U8 { unsigned u[4]; short8 s; };

__device__ __forceinline__ unsigned short f2bf(float x) {
  unsigned u = __float_as_uint(x);
  unsigned r = u + 0x7fffu + ((u >> 16) & 1u);  // RNE
  return (unsigned short)(r >> 16);
}
__device__ __forceinline__ unsigned pk2(float lo, float hi) {
  return (unsigned)f2bf(lo) | ((unsigned)f2bf(hi) << 16);
}
// split x into bf16 hi + bf16 lo (x ~= hi + lo)
__device__ __forceinline__ void split2(float x, unsigned short& h,
                                       unsigned short& l) {
  h = f2bf(x);
  const float hf = __uint_as_float(((unsigned)h) << 16);
  l = f2bf(x - hf);
}
__device__ __forceinline__ void split_pk2(float a, float b, unsigned& hw,
                                          unsigned& lw) {
  unsigned short ah, al, bh_, bl;
  split2(a, ah, al);
  split2(b, bh_, bl);
  hw = (unsigned)ah | ((unsigned)bh_ << 16);
  lw = (unsigned)al | ((unsigned)bl << 16);
}
__device__ __forceinline__ f32x16 zero16() {
  f32x16 z;
#pragma unroll
  for (int i = 0; i < 16; ++i) z[i] = 0.f;
  return z;
}

// P -> MFMA-A fragment relayout for one 16-key slot (exchange across lane^32).
#define MK_PA(dst, hi_, a0,a1,a2,a3,a4,a5,a6,a7)                         \
  {                                                                      \
    unsigned x0 = pk2(a0, a1), x1 = pk2(a2, a3);                         \
    unsigned y0 = pk2(a4, a5), y1 = pk2(a6, a7);                         \
    unsigned t0 = (unsigned)__shfl_xor((int)((hi_) ? x0 : y0), 32);      \
    if (hi_) x0 = t0; else y0 = t0;                                      \
    unsigned t1 = (unsigned)__shfl_xor((int)((hi_) ? x1 : y1), 32);      \
    if (hi_) x1 = t1; else y1 = t1;                                      \
    U8 w_; w_.u[0] = x0; w_.u[1] = x1; w_.u[2] = y0; w_.u[3] = y1;       \
    dst = w_.s;                                                          \
  }

// ---------------------------------------------------------------------------
__global__ void k_setup(const int* __restrict__ mask,
                        int* __restrict__ gpos, int* __restrict__ gcount) {
  const int b = blockIdx.x;
  const int t = threadIdx.x;  // 64
  __shared__ int cnt[64];
  if (t < CG) gpos[b * CG + t] = 0;
  const int span = CS / 64;
  const int base = b * CS + t * span;
  int c = 0;
  for (int i = 0; i < span; ++i) c += (mask[base + i] > 0) ? 1 : 0;
  cnt[t] = c;
  __syncthreads();
  int pre = 0;
  for (int j = 0; j < t; ++j) pre += cnt[j];
  for (int i = 0; i < span; ++i) {
    if (mask[base + i] > 0) {
      if (pre < CG) gpos[b * CG + pre] = t * span + i;
      ++pre;
    }
  }
  if (t == 63) gcount[b] = (pre < CG) ? pre : CG;
}

// ---------------------------------------------------------------------------
// Part 1 (unchanged from round 4): every query attends to the 64 compacted
// global KVs. Split-precision QK^T; bf16 PV via transposed V in LDS.
// ---------------------------------------------------------------------------
__global__ __launch_bounds__(256) void k_local(
    const float* __restrict__ q, const float* __restrict__ k,
    const float* __restrict__ v,
    const int* __restrict__ gpos, const int* __restrict__ gcount,
    float* __restrict__ ctx, float* __restrict__ probs) {
  __shared__ __align__(16) short sKh[64 * 64];
  __shared__ __align__(16) short sKl[64 * 64];
  __shared__ __align__(16) short sVT[64 * 64];
  __shared__ int gp[CG];
  __shared__ int gc_s;
  const int bh = blockIdx.y, b = bh / CH, t = threadIdx.x;
  if (t < CG) gp[t] = gpos[b * CG + t];
  if (t == 0) gc_s = gcount[b];
  __syncthreads();

  if (t < 128) {  // stage K rows -> sKh/sKl [key][d]
    const int row = t >> 1, c0 = (t & 1) * 32;
    const float* src = k + ((size_t)(bh * CS + gp[row])) * CD + c0;
    const unsigned swz = (unsigned)((row & 7) << 4);
    char* rbh = (char*)sKh + row * 128;
    char* rbl = (char*)sKl + row * 128;
#pragma unroll
    for (int i = 0; i < 4; ++i) {
      fvec4 a = *(const fvec4*)(src + i * 8);
      fvec4 c = *(const fvec4*)(src + i * 8 + 4);
      U8 wh, wl;
      split_pk2(a[0], a[1], wh.u[0], wl.u[0]);
      split_pk2(a[2], a[3], wh.u[1], wl.u[1]);
      split_pk2(c[0], c[1], wh.u[2], wl.u[2]);
      split_pk2(c[2], c[3], wh.u[3], wl.u[3]);
      const unsigned off = ((unsigned)(c0 * 2 + i * 16)) ^ swz;
      *(short8*)(rbh + off) = wh.s;
      *(short8*)(rbl + off) = wl.s;
    }
  } else {  // stage V transposed -> sVT[d][key]
    const int u = t - 128;
    const int kg = u >> 4, cg = u & 15;
    fvec4 rv[8];
#pragma unroll
    for (int i = 0; i < 8; ++i)
      rv[i] = *(const fvec4*)(v + ((size_t)(bh * CS + gp[8 * kg + i])) * CD + 4 * cg);
#pragma unroll
    for (int c = 0; c < 4; ++c) {
      const int row = 4 * cg + c;
      U8 w;
      w.u[0] = pk2(rv[0][c], rv[1][c]); w.u[1] = pk2(rv[2][c], rv[3][c]);
      w.u[2] = pk2(rv[4][c], rv[5][c]); w.u[3] = pk2(rv[6][c], rv[7][c]);
      *(short8*)((char*)sVT + row * 128 +
                 (((unsigned)(16 * kg)) ^ ((unsigned)((row & 7) << 4)))) = w.s;
    }
  }
  __syncthreads();

  const int lane = t & 63, wv = t >> 6;
  const int hi = lane >> 5, ql = lane & 31;
  const int qrow = blockIdx.x * 128 + wv * 32 + ql;

  const float* qr = q + ((size_t)(bh * CS + qrow)) * CD + hi * 8;
  short8 qh[4], qlo[4];
#pragma unroll
  for (int s = 0; s < 4; ++s) {
    fvec4 a = *(const fvec4*)(qr + s * 16);
    fvec4 c = *(const fvec4*)(qr + s * 16 + 4);
    U8 wh, wl;
    split_pk2(a[0] * 0.125f, a[1] * 0.125f, wh.u[0], wl.u[0]);
    split_pk2(a[2] * 0.125f, a[3] * 0.125f, wh.u[1], wl.u[1]);
    split_pk2(c[0] * 0.125f, c[1] * 0.125f, wh.u[2], wl.u[2]);
    split_pk2(c[2] * 0.125f, c[3] * 0.125f, wh.u[3], wl.u[3]);
    qh[s] = wh.s;
    qlo[s] = wl.s;
  }

  f32x16 acc0 = zero16(), acc1 = zero16();
  const unsigned kswz = (unsigned)((ql & 7) << 4);
#pragma unroll
  for (int s = 0; s < 4; ++s) {
    const unsigned off = ((unsigned)(32 * s + 16 * hi)) ^ kswz;
    short8 kh0 = *(const short8*)((char*)sKh + ql * 128 + off);
    short8 kl0 = *(const short8*)((char*)sKl + ql * 128 + off);
    acc0 = __builtin_amdgcn_mfma_f32_32x32x16_bf16(kh0, qh[s], acc0, 0, 0, 0);
    acc0 = __builtin_amdgcn_mfma_f32_32x32x16_bf16(kl0, qh[s], acc0, 0, 0, 0);
    acc0 = __builtin_amdgcn_mfma_f32_32x32x16_bf16(kh0, qlo[s], acc0, 0, 0, 0);
    short8 kh1 = *(const short8*)((char*)sKh + (32 + ql) * 128 + off);
    short8 kl1 = *(const short8*)((char*)sKl + (32 + ql) * 128 + off);
    acc1 = __builtin_amdgcn_mfma_f32_32x32x16_bf16(kh1, qh[s], acc1, 0, 0, 0);
    acc1 = __builtin_amdgcn_mfma_f32_32x32x16_bf16(kl1, qh[s], acc1, 0, 0, 0);
    acc1 = __builtin_amdgcn_mfma_f32_32x32x16_bf16(kh1, qlo[s], acc1, 0, 0, 0);
  }

  const int gc = gc_s;
  float p0[16], p1[16];
  float m = -1e30f;
#pragma unroll
  for (int r = 0; r < 16; ++r) {
    const int key0 = (r & 3) + 8 * (r >> 2) + 4 * hi;
    float x0 = (key0 < gc) ? acc0[r] : -1e30f;
    float x1 = (key0 + 32 < gc) ? acc1[r] : -1e30f;
    p0[r] = x0; p1[r] = x1;
    m = fmaxf(m, fmaxf(x0, x1));
  }
  m = fmaxf(m, __shfl_xor(m, 32));
  float ls = 0.f;
#pragma unroll
  for (int r = 0; r < 16; ++r) {
    p0[r] = __expf(p0[r] - m); ls += p0[r];
    p1[r] = __expf(p1[r] - m); ls += p1[r];
  }
  ls += __shfl_xor(ls, 32);
  const float inv = 1.0f / ls;
#pragma unroll
  for (int r = 0; r < 16; ++r) { p0[r] *= inv; p1[r] *= inv; }

  float* prow = probs + ((size_t)(bh * CS + qrow)) * CG;
#pragma unroll
  for (int g4 = 0; g4 < 4; ++g4) {
    fvec4 o0 = {p0[4 * g4], p0[4 * g4 + 1], p0[4 * g4 + 2], p0[4 * g4 + 3]};
    fvec4 o1 = {p1[4 * g4], p1[4 * g4 + 1], p1[4 * g4 + 2], p1[4 * g4 + 3]};
    *(fvec4*)(prow + 8 * g4 + 4 * hi) = o0;
    *(fvec4*)(prow + 8 * g4 + 4 * hi + 32) = o1;
  }

  short8 pa0, pa1, pa2, pa3;
  MK_PA(pa0, hi, p0[0], p0[1], p0[2], p0[3], p0[4], p0[5], p0[6], p0[7]);
  MK_PA(pa1, hi, p0[8], p0[9], p0[10], p0[11], p0[12], p0[13], p0[14], p0[15]);
  MK_PA(pa2, hi, p1[0], p1[1], p1[2], p1[3], p1[4], p1[5], p1[6], p1[7]);
  MK_PA(pa3, hi, p1[8], p1[9], p1[10], p1[11], p1[12], p1[13], p1[14], p1[15]);

  f32x16 oc0 = zero16(), oc1 = zero16();
#pragma unroll
  for (int s = 0; s < 4; ++s) {
    const short8 pas = (s == 0) ? pa0 : (s == 1) ? pa1 : (s == 2) ? pa2 : pa3;
    const unsigned off = ((unsigned)(32 * s + 16 * hi)) ^ kswz;
    short8 v0 = *(const short8*)((char*)sVT + ql * 128 + off);
    oc0 = __builtin_amdgcn_mfma_f32_32x32x16_bf16(pas, v0, oc0, 0, 0, 0);
    short8 v1 = *(const short8*)((char*)sVT + (32 + ql) * 128 + off);
    oc1 = __builtin_amdgcn_mfma_f32_32x32x16_bf16(pas, v1, oc1, 0, 0, 0);
  }

  float* cb = ctx + ((size_t)(bh * CS + blockIdx.x * 128 + wv * 32)) * CD;
#pragma unroll
  for (int r = 0; r < 16; ++r) {
    const int qr2 = (r & 3) + 8 * (r >> 2) + 4 * hi;
    cb[(size_t)qr2 * CD + ql] = oc0[r];
    cb[(size_t)qr2 * CD + 32 + ql] = oc1[r];
  }
}

// ---------------------------------------------------------------------------
// Part 2, rebuilt as a minimal-delta clone of the verified part-1 path.
// Block = 128-key window = TWO independent part-1-style 64x64 tile pairs.
// Wave (qt,kh): one-shot softmax of 32 global q's over 64 keys (half kh),
// flash partials (m, l, unnormalized ctx in bf16) to workspace. NPART=64.
// ---------------------------------------------------------------------------
__global__ __launch_bounds__(256) void k_gpart(
    const float* __restrict__ q, const float* __restrict__ k,
    const float* __restrict__ v,
    const int* __restrict__ gpos,
    float* __restrict__ pm, float* __restrict__ pl,
    unsigned short* __restrict__ pctx) {
  __shared__ __align__(16) short sK2[2][64 * 64];
  __shared__ __align__(16) short sVT2[2][64 * 64];
  __shared__ int gp[CG];
  const int bh = blockIdx.y, bx = blockIdx.x, t = threadIdx.x;
  const int b = bh / CH;
  if (t < CG) gp[t] = gpos[b * CG + t];
  __syncthreads();

  const int kwin = bx * 128;
#pragma unroll
  for (int h = 0; h < 2; ++h) {
    if (t < 128) {  // stage K rows -> sK2[h][key][d]  (exact part-1 staging)
      const int row = t >> 1, c0 = (t & 1) * 32;
      const float* src = k + ((size_t)(bh * CS + kwin + h * 64 + row)) * CD + c0;
      const unsigned swz = (unsigned)((row & 7) << 4);
      char* rb = (char*)sK2[h] + row * 128;
#pragma unroll
      for (int i = 0; i < 4; ++i) {
        fvec4 a = *(const fvec4*)(src + i * 8);
        fvec4 c = *(const fvec4*)(src + i * 8 + 4);
        U8 w;
        w.u[0] = pk2(a[0], a[1]); w.u[1] = pk2(a[2], a[3]);
        w.u[2] = pk2(c[0], c[1]); w.u[3] = pk2(c[2], c[3]);
        *(short8*)(rb + (((unsigned)(c0 * 2 + i * 16)) ^ swz)) = w.s;
      }
    } else {  // stage V transposed -> sVT2[h][d][key]
      const int u = t - 128;
      const int kg = u >> 4, cg = u & 15;
      fvec4 rv[8];
#pragma unroll
      for (int i = 0; i < 8; ++i)
        rv[i] = *(const fvec4*)(
            v + ((size_t)(bh * CS + kwin + h * 64 + 8 * kg + i)) * CD + 4 * cg);
#pragma unroll
      for (int c = 0; c < 4; ++c) {
        const int row = 4 * cg + c;
        U8 w;
        w.u[0] = pk2(rv[0][c], rv[1][c]); w.u[1] = pk2(rv[2][c], rv[3][c]);
        w.u[2] = pk2(rv[4][c], rv[5][c]); w.u[3] = pk2(rv[6][c], rv[7][c]);
        *(short8*)((char*)sVT2[h] + row * 128 +
                   (((unsigned)(16 * kg)) ^ ((unsigned)((row & 7) << 4)))) = w.s;
      }
    }
  }
  __syncthreads();

  const int lane = t & 63, wv = t >> 6;
  const int hi = lane >> 5, ql = lane & 31;
  const int qt = wv & 1, kh = wv >> 1;
  const int qslot = qt * 32 + ql;
  const char* bK = (const char*)sK2[kh];
  const char* bVT = (const char*)sVT2[kh];

  const float* qr = q + ((size_t)(bh * CS + gp[qslot])) * CD + hi * 8;
  short8 qf[4];
#pragma unroll
  for (int s = 0; s < 4; ++s) {
    fvec4 a = *(const fvec4*)(qr + s * 16);
    fvec4 c = *(const fvec4*)(qr + s * 16 + 4);
    U8 w;
    w.u[0] = pk2(a[0] * 0.125f, a[1] * 0.125f);
    w.u[1] = pk2(a[2] * 0.125f, a[3] * 0.125f);
    w.u[2] = pk2(c[0] * 0.125f, c[1] * 0.125f);
    w.u[3] = pk2(c[2] * 0.125f, c[3] * 0.125f);
    qf[s] = w.s;
  }

  // QK^T (exact part-1 read pattern)
  f32x16 acc0 = zero16(), acc1 = zero16();
  const unsigned kswz = (unsigned)((ql & 7) << 4);
#pragma unroll
  for (int s = 0; s < 4; ++s) {
    const unsigned off = ((unsigned)(32 * s + 16 * hi)) ^ kswz;
    short8 k0 = *(const short8*)(bK + ql * 128 + off);
    acc0 = __builtin_amdgcn_mfma_f32_32x32x16_bf16(k0, qf[s], acc0, 0, 0, 0);
    short8 k1 = *(const short8*)(bK + (32 + ql) * 128 + off);
    acc1 = __builtin_amdgcn_mfma_f32_32x32x16_bf16(k1, qf[s], acc1, 0, 0, 0);
  }

  // one-shot softmax over this wave's 64 keys (no mask, no normalization)
  float p0[16], p1[16];
  float m = -1e30f;
#pragma unroll
  for (int r = 0; r < 16; ++r) {
    p0[r] = acc0[r]; p1[r] = acc1[r];
    m = fmaxf(m, fmaxf(p0[r], p1[r]));
  }
  m = fmaxf(m, __shfl_xor(m, 32));
  float ls = 0.f;
#pragma unroll
  for (int r = 0; r < 16; ++r) {
    p0[r] = __expf(p0[r] - m); ls += p0[r];
    p1[r] = __expf(p1[r] - m); ls += p1[r];
  }
  ls += __shfl_xor(ls, 32);

  short8 pa0, pa1, pa2, pa3;
  MK_PA(pa0, hi, p0[0], p0[1], p0[2], p0[3], p0[4], p0[5], p0[6], p0[7]);
  MK_PA(pa1, hi, p0[8], p0[9], p0[10], p0[11], p0[12], p0[13], p0[14], p0[15]);
  MK_PA(pa2, hi, p1[0], p1[1], p1[2], p1[3], p1[4], p1[5], p1[6], p1[7]);
  MK_PA(pa3, hi, p1[8], p1[9], p1[10], p1[11], p1[12], p1[13], p1[14], p1[15]);

  f32x16 oc0 = zero16(), oc1 = zero16();
#pragma unroll
  for (int s = 0; s < 4; ++s) {
    const short8 pas = (s == 0) ? pa0 : (s == 1) ? pa1 : (s == 2) ? pa2 : pa3;
    const unsigned off = ((unsigned)(32 * s + 16 * hi)) ^ kswz;
    short8 v0 = *(const short8*)(bVT + ql * 128 + off);
    oc0 = __builtin_amdgcn_mfma_f32_32x32x16_bf16(pas, v0, oc0, 0, 0, 0);
    short8 v1 = *(const short8*)(bVT + (32 + ql) * 128 + off);
    oc1 = __builtin_amdgcn_mfma_f32_32x32x16_bf16(pas, v1, oc1, 0, 0, 0);
  }

  const int part = bx * 2 + kh;
  if (hi == 0) {
    const size_t o = ((size_t)(bh * NPART + part)) * CG + qslot;
    pm[o] = m;
    pl[o] = ls;
  }
  unsigned short* po =
      pctx + (((size_t)(bh * NPART + part)) * CG + qt * 32) * CD;
#pragma unroll
  for (int r = 0; r < 16; ++r) {
    const int qr2 = (r & 3) + 8 * (r >> 2) + 4 * hi;
    po[(size_t)qr2 * CD + ql] = f2bf(oc0[r]);
    po[(size_t)qr2 * CD + 32 + ql] = f2bf(oc1[r]);
  }
}

// ---------------------------------------------------------------------------
__global__ __launch_bounds__(64) void k_combine(
    const float* __restrict__ pm, const float* __restrict__ pl,
    const unsigned short* __restrict__ pctx,
    const int* __restrict__ gpos, const int* __restrict__ gcount,
    float* __restrict__ ctx) {
  const int g = blockIdx.x;
  const int bh = blockIdx.y;
  const int b = bh / CH;
  if (g >= gcount[b]) return;
  const int d = threadIdx.x;
  float m = -1e30f;
  for (int c = 0; c < NPART; ++c)
    m = fmaxf(m, pm[((size_t)(bh * NPART + c)) * CG + g]);
  float L = 0.f, acc = 0.f;
  for (int c = 0; c < NPART; ++c) {
    const size_t o = ((size_t)(bh * NPART + c)) * CG + g;
    const float w = __expf(pm[o] - m);
    L = fmaf(w, pl[o], L);
    const float x = __uint_as_float((unsigned)pctx[o * CD + d] << 16);
    acc = fmaf(w, x, acc);
  }
  const int tok = gpos[b * CG + g];
  ctx[((size_t)(bh * CS + tok)) * CD + d] = acc / L;
}

extern "C" void kernel_launch(void* const* d_in, const int* in_sizes, int n_in,
                              void* d_out, int out_size, void* d_ws, size_t ws_size,
                              hipStream_t stream) {
  const float* q = (const float*)d_in[0];
  const float* k = (const float*)d_in[1];
  const float* v = (const float*)d_in[2];
  const int* mask = (const int*)d_in[3];

  float* ctx = (float*)d_out;
  float* probs = ctx + (size_t)CBH * CS * CD;

  char* ws = (char*)d_ws;
  int* gpos = (int*)ws;                                  // 512 B
  int* gcount = (int*)(ws + 512);                        // 512 B
  float* pm = (float*)(ws + 1024);                       // CBH*NPART*CG f32
  float* pl = pm + (size_t)CBH * NPART * CG;             // CBH*NPART*CG f32
  unsigned short* pctx =
      (unsigned short*)(pl + (size_t)CBH * NPART * CG);  // CBH*NPART*CG*CD bf16

  k_setup<<<dim3(CB), dim3(64), 0, stream>>>(mask, gpos, gcount);
  k_local<<<dim3(CS / 128, CBH), dim3(256), 0, stream>>>(
      q, k, v, gpos, gcount, ctx, probs);
  k_gpart<<<dim3(G2NCH, CBH), dim3(256), 0, stream>>>(
      q, k, v, gpos, pm, pl, pctx);
  k_combine<<<dim3(CG, CBH), dim3(64), 0, stream>>>(
      pm, pl, pctx, gpos, gcount, ctx);
}

// Round 6
// 73.598 us; speedup vs baseline: 4.0266x; 1.0819x over previous
//
#include <hip/hip_runtime.h>
#include <cstddef>

constexpr int CB  = 2;
constexpr int CH  = 16;
constexpr int CS  = 4096;
constexpr int CD  = 64;
constexpr int CG  = 64;
constexpr int CBH = CB * CH;
constexpr int NW1   = CS / 128;   // part-1 windows per bh (32)
constexpr int G2NCH = 32;         // part-2 128-key windows per bh
constexpr int NPART = G2NCH * 2;  // partials per (bh,q)

typedef float  f32x16 __attribute__((ext_vector_type(16)));
typedef short  short8 __attribute__((ext_vector_type(8)));
typedef float  fvec4  __attribute__((ext_vector_type(4)));

union U8 { unsigned u[4]; short8 s; };

__device__ __forceinline__ unsigned short f2bf(float x) {
  unsigned u = __float_as_uint(x);
  unsigned r = u + 0x7fffu + ((u >> 16) & 1u);  // RNE
  return (unsigned short)(r >> 16);
}
__device__ __forceinline__ unsigned pk2(float lo, float hi) {
  return (unsigned)f2bf(lo) | ((unsigned)f2bf(hi) << 16);
}
__device__ __forceinline__ f32x16 zero16() {
  f32x16 z;
#pragma unroll
  for (int i = 0; i < 16; ++i) z[i] = 0.f;
  return z;
}

// P -> MFMA-A fragment relayout for one 16-key slot (exchange across lane^32).
#define MK_PA(dst, hi_, a0,a1,a2,a3,a4,a5,a6,a7)                         \
  {                                                                      \
    unsigned x0 = pk2(a0, a1), x1 = pk2(a2, a3);                         \
    unsigned y0 = pk2(a4, a5), y1 = pk2(a6, a7);                         \
    unsigned t0 = (unsigned)__shfl_xor((int)((hi_) ? x0 : y0), 32);      \
    if (hi_) x0 = t0; else y0 = t0;                                      \
    unsigned t1 = (unsigned)__shfl_xor((int)((hi_) ? x1 : y1), 32);      \
    if (hi_) x1 = t1; else y1 = t1;                                      \
    U8 w_; w_.u[0] = x0; w_.u[1] = x1; w_.u[2] = y0; w_.u[3] = y1;       \
    dst = w_.s;                                                          \
  }

// ---------------------------------------------------------------------------
__global__ void k_setup(const int* __restrict__ mask,
                        int* __restrict__ gpos, int* __restrict__ gcount) {
  const int b = blockIdx.x;
  const int t = threadIdx.x;  // 64
  __shared__ int cnt[64];
  if (t < CG) gpos[b * CG + t] = 0;
  const int span = CS / 64;
  const int base = b * CS + t * span;
  int c = 0;
  for (int i = 0; i < span; ++i) c += (mask[base + i] > 0) ? 1 : 0;
  cnt[t] = c;
  __syncthreads();
  int pre = 0;
  for (int j = 0; j < t; ++j) pre += cnt[j];
  for (int i = 0; i < span; ++i) {
    if (mask[base + i] > 0) {
      if (pre < CG) gpos[b * CG + pre] = t * span + i;
      ++pre;
    }
  }
  if (t == 63) gcount[b] = (pre < CG) ? pre : CG;
}

// ---------------------------------------------------------------------------
// Fused main kernel. blockIdx.x < NW1: part-1 role (128 q-rows x 64 global
// KVs). Else: part-2 role (64 global q x this block's 128-key window),
// byte-identical compute to the verified r5 k_gpart.
// ---------------------------------------------------------------------------
union __align__(16) SMem {
  struct { short sK[64 * 64]; short sVT[64 * 64]; } p1;            // 16 KB
  struct { short sK2[2][64 * 64]; short sVT2[2][64 * 64]; } p2;    // 32 KB
};

__global__ __launch_bounds__(256) void k_main(
    const float* __restrict__ q, const float* __restrict__ k,
    const float* __restrict__ v,
    const int* __restrict__ gpos, const int* __restrict__ gcount,
    float* __restrict__ ctx, float* __restrict__ probs,
    float* __restrict__ pm, float* __restrict__ pl,
    unsigned short* __restrict__ pctx) {
  __shared__ SMem sm;
  __shared__ int gp[CG];
  __shared__ int gc_s;
  const int bh = blockIdx.y, b = bh / CH, t = threadIdx.x;
  if (t < CG) gp[t] = gpos[b * CG + t];
  if (t == 0) gc_s = gcount[b];
  __syncthreads();

  const int lane = t & 63, wv = t >> 6;
  const int hi = lane >> 5, ql = lane & 31;
  const unsigned kswz = (unsigned)((ql & 7) << 4);

  if (blockIdx.x < NW1) {
    // ------------------------------ part 1 ------------------------------
    if (t < 128) {  // stage gathered K rows -> sK[key][d] (bf16, swizzled)
      const int row = t >> 1, c0 = (t & 1) * 32;
      const float* src = k + ((size_t)(bh * CS + gp[row])) * CD + c0;
      const unsigned swz = (unsigned)((row & 7) << 4);
      char* rb = (char*)sm.p1.sK + row * 128;
#pragma unroll
      for (int i = 0; i < 4; ++i) {
        fvec4 a = *(const fvec4*)(src + i * 8);
        fvec4 c = *(const fvec4*)(src + i * 8 + 4);
        U8 w;
        w.u[0] = pk2(a[0], a[1]); w.u[1] = pk2(a[2], a[3]);
        w.u[2] = pk2(c[0], c[1]); w.u[3] = pk2(c[2], c[3]);
        *(short8*)(rb + (((unsigned)(c0 * 2 + i * 16)) ^ swz)) = w.s;
      }
    } else {  // stage gathered V transposed -> sVT[d][key]
      const int u = t - 128;
      const int kg = u >> 4, cg = u & 15;
      fvec4 rv[8];
#pragma unroll
      for (int i = 0; i < 8; ++i)
        rv[i] = *(const fvec4*)(v + ((size_t)(bh * CS + gp[8 * kg + i])) * CD + 4 * cg);
#pragma unroll
      for (int c = 0; c < 4; ++c) {
        const int row = 4 * cg + c;
        U8 w;
        w.u[0] = pk2(rv[0][c], rv[1][c]); w.u[1] = pk2(rv[2][c], rv[3][c]);
        w.u[2] = pk2(rv[4][c], rv[5][c]); w.u[3] = pk2(rv[6][c], rv[7][c]);
        *(short8*)((char*)sm.p1.sVT + row * 128 +
                   (((unsigned)(16 * kg)) ^ ((unsigned)((row & 7) << 4)))) = w.s;
      }
    }
    __syncthreads();

    const int qrow = blockIdx.x * 128 + wv * 32 + ql;
    const float* qr = q + ((size_t)(bh * CS + qrow)) * CD + hi * 8;
    short8 qf[4];
#pragma unroll
    for (int s = 0; s < 4; ++s) {
      fvec4 a = *(const fvec4*)(qr + s * 16);
      fvec4 c = *(const fvec4*)(qr + s * 16 + 4);
      U8 w;
      w.u[0] = pk2(a[0] * 0.125f, a[1] * 0.125f);
      w.u[1] = pk2(a[2] * 0.125f, a[3] * 0.125f);
      w.u[2] = pk2(c[0] * 0.125f, c[1] * 0.125f);
      w.u[3] = pk2(c[2] * 0.125f, c[3] * 0.125f);
      qf[s] = w.s;
    }

    f32x16 acc0 = zero16(), acc1 = zero16();
#pragma unroll
    for (int s = 0; s < 4; ++s) {
      const unsigned off = ((unsigned)(32 * s + 16 * hi)) ^ kswz;
      short8 k0 = *(const short8*)((char*)sm.p1.sK + ql * 128 + off);
      acc0 = __builtin_amdgcn_mfma_f32_32x32x16_bf16(k0, qf[s], acc0, 0, 0, 0);
      short8 k1 = *(const short8*)((char*)sm.p1.sK + (32 + ql) * 128 + off);
      acc1 = __builtin_amdgcn_mfma_f32_32x32x16_bf16(k1, qf[s], acc1, 0, 0, 0);
    }

    const int gc = gc_s;
    float p0[16], p1[16];
    float m = -1e30f;
#pragma unroll
    for (int r = 0; r < 16; ++r) {
      const int key0 = (r & 3) + 8 * (r >> 2) + 4 * hi;
      float x0 = (key0 < gc) ? acc0[r] : -1e30f;
      float x1 = (key0 + 32 < gc) ? acc1[r] : -1e30f;
      p0[r] = x0; p1[r] = x1;
      m = fmaxf(m, fmaxf(x0, x1));
    }
    m = fmaxf(m, __shfl_xor(m, 32));
    float ls = 0.f;
#pragma unroll
    for (int r = 0; r < 16; ++r) {
      p0[r] = __expf(p0[r] - m); ls += p0[r];
      p1[r] = __expf(p1[r] - m); ls += p1[r];
    }
    ls += __shfl_xor(ls, 32);
    const float inv = 1.0f / ls;
#pragma unroll
    for (int r = 0; r < 16; ++r) { p0[r] *= inv; p1[r] *= inv; }

    float* prow = probs + ((size_t)(bh * CS + qrow)) * CG;
#pragma unroll
    for (int g4 = 0; g4 < 4; ++g4) {
      fvec4 o0 = {p0[4 * g4], p0[4 * g4 + 1], p0[4 * g4 + 2], p0[4 * g4 + 3]};
      fvec4 o1 = {p1[4 * g4], p1[4 * g4 + 1], p1[4 * g4 + 2], p1[4 * g4 + 3]};
      *(fvec4*)(prow + 8 * g4 + 4 * hi) = o0;
      *(fvec4*)(prow + 8 * g4 + 4 * hi + 32) = o1;
    }

    short8 pa0, pa1, pa2, pa3;
    MK_PA(pa0, hi, p0[0], p0[1], p0[2], p0[3], p0[4], p0[5], p0[6], p0[7]);
    MK_PA(pa1, hi, p0[8], p0[9], p0[10], p0[11], p0[12], p0[13], p0[14], p0[15]);
    MK_PA(pa2, hi, p1[0], p1[1], p1[2], p1[3], p1[4], p1[5], p1[6], p1[7]);
    MK_PA(pa3, hi, p1[8], p1[9], p1[10], p1[11], p1[12], p1[13], p1[14], p1[15]);

    f32x16 oc0 = zero16(), oc1 = zero16();
#pragma unroll
    for (int s = 0; s < 4; ++s) {
      const short8 pas = (s == 0) ? pa0 : (s == 1) ? pa1 : (s == 2) ? pa2 : pa3;
      const unsigned off = ((unsigned)(32 * s + 16 * hi)) ^ kswz;
      short8 v0 = *(const short8*)((char*)sm.p1.sVT + ql * 128 + off);
      oc0 = __builtin_amdgcn_mfma_f32_32x32x16_bf16(pas, v0, oc0, 0, 0, 0);
      short8 v1 = *(const short8*)((char*)sm.p1.sVT + (32 + ql) * 128 + off);
      oc1 = __builtin_amdgcn_mfma_f32_32x32x16_bf16(pas, v1, oc1, 0, 0, 0);
    }

    float* cb = ctx + ((size_t)(bh * CS + blockIdx.x * 128 + wv * 32)) * CD;
#pragma unroll
    for (int r = 0; r < 16; ++r) {
      const int qr2 = (r & 3) + 8 * (r >> 2) + 4 * hi;
      cb[(size_t)qr2 * CD + ql] = oc0[r];
      cb[(size_t)qr2 * CD + 32 + ql] = oc1[r];
    }
  } else {
    // ------------------------------ part 2 ------------------------------
    const int bx = blockIdx.x - NW1;
    const int kwin = bx * 128;
#pragma unroll
    for (int h = 0; h < 2; ++h) {
      if (t < 128) {  // stage K rows -> sK2[h][key][d]
        const int row = t >> 1, c0 = (t & 1) * 32;
        const float* src =
            k + ((size_t)(bh * CS + kwin + h * 64 + row)) * CD + c0;
        const unsigned swz = (unsigned)((row & 7) << 4);
        char* rb = (char*)sm.p2.sK2[h] + row * 128;
#pragma unroll
        for (int i = 0; i < 4; ++i) {
          fvec4 a = *(const fvec4*)(src + i * 8);
          fvec4 c = *(const fvec4*)(src + i * 8 + 4);
          U8 w;
          w.u[0] = pk2(a[0], a[1]); w.u[1] = pk2(a[2], a[3]);
          w.u[2] = pk2(c[0], c[1]); w.u[3] = pk2(c[2], c[3]);
          *(short8*)(rb + (((unsigned)(c0 * 2 + i * 16)) ^ swz)) = w.s;
        }
      } else {  // stage V transposed -> sVT2[h][d][key]
        const int u = t - 128;
        const int kg = u >> 4, cg = u & 15;
        fvec4 rv[8];
#pragma unroll
        for (int i = 0; i < 8; ++i)
          rv[i] = *(const fvec4*)(
              v + ((size_t)(bh * CS + kwin + h * 64 + 8 * kg + i)) * CD + 4 * cg);
#pragma unroll
        for (int c = 0; c < 4; ++c) {
          const int row = 4 * cg + c;
          U8 w;
          w.u[0] = pk2(rv[0][c], rv[1][c]); w.u[1] = pk2(rv[2][c], rv[3][c]);
          w.u[2] = pk2(rv[4][c], rv[5][c]); w.u[3] = pk2(rv[6][c], rv[7][c]);
          *(short8*)((char*)sm.p2.sVT2[h] + row * 128 +
                     (((unsigned)(16 * kg)) ^ ((unsigned)((row & 7) << 4)))) = w.s;
        }
      }
    }
    __syncthreads();

    const int qt = wv & 1, kh = wv >> 1;
    const int qslot = qt * 32 + ql;
    const char* bK = (const char*)sm.p2.sK2[kh];
    const char* bVT = (const char*)sm.p2.sVT2[kh];

    const float* qr = q + ((size_t)(bh * CS + gp[qslot])) * CD + hi * 8;
    short8 qf[4];
#pragma unroll
    for (int s = 0; s < 4; ++s) {
      fvec4 a = *(const fvec4*)(qr + s * 16);
      fvec4 c = *(const fvec4*)(qr + s * 16 + 4);
      U8 w;
      w.u[0] = pk2(a[0] * 0.125f, a[1] * 0.125f);
      w.u[1] = pk2(a[2] * 0.125f, a[3] * 0.125f);
      w.u[2] = pk2(c[0] * 0.125f, c[1] * 0.125f);
      w.u[3] = pk2(c[2] * 0.125f, c[3] * 0.125f);
      qf[s] = w.s;
    }

    f32x16 acc0 = zero16(), acc1 = zero16();
#pragma unroll
    for (int s = 0; s < 4; ++s) {
      const unsigned off = ((unsigned)(32 * s + 16 * hi)) ^ kswz;
      short8 k0 = *(const short8*)(bK + ql * 128 + off);
      acc0 = __builtin_amdgcn_mfma_f32_32x32x16_bf16(k0, qf[s], acc0, 0, 0, 0);
      short8 k1 = *(const short8*)(bK + (32 + ql) * 128 + off);
      acc1 = __builtin_amdgcn_mfma_f32_32x32x16_bf16(k1, qf[s], acc1, 0, 0, 0);
    }

    float p0[16], p1[16];
    float m = -1e30f;
#pragma unroll
    for (int r = 0; r < 16; ++r) {
      p0[r] = acc0[r]; p1[r] = acc1[r];
      m = fmaxf(m, fmaxf(p0[r], p1[r]));
    }
    m = fmaxf(m, __shfl_xor(m, 32));
    float ls = 0.f;
#pragma unroll
    for (int r = 0; r < 16; ++r) {
      p0[r] = __expf(p0[r] - m); ls += p0[r];
      p1[r] = __expf(p1[r] - m); ls += p1[r];
    }
    ls += __shfl_xor(ls, 32);

    short8 pa0, pa1, pa2, pa3;
    MK_PA(pa0, hi, p0[0], p0[1], p0[2], p0[3], p0[4], p0[5], p0[6], p0[7]);
    MK_PA(pa1, hi, p0[8], p0[9], p0[10], p0[11], p0[12], p0[13], p0[14], p0[15]);
    MK_PA(pa2, hi, p1[0], p1[1], p1[2], p1[3], p1[4], p1[5], p1[6], p1[7]);
    MK_PA(pa3, hi, p1[8], p1[9], p1[10], p1[11], p1[12], p1[13], p1[14], p1[15]);

    f32x16 oc0 = zero16(), oc1 = zero16();
#pragma unroll
    for (int s = 0; s < 4; ++s) {
      const short8 pas = (s == 0) ? pa0 : (s == 1) ? pa1 : (s == 2) ? pa2 : pa3;
      const unsigned off = ((unsigned)(32 * s + 16 * hi)) ^ kswz;
      short8 v0 = *(const short8*)(bVT + ql * 128 + off);
      oc0 = __builtin_amdgcn_mfma_f32_32x32x16_bf16(pas, v0, oc0, 0, 0, 0);
      short8 v1 = *(const short8*)(bVT + (32 + ql) * 128 + off);
      oc1 = __builtin_amdgcn_mfma_f32_32x32x16_bf16(pas, v1, oc1, 0, 0, 0);
    }

    const int part = bx * 2 + kh;
    if (hi == 0) {
      const size_t o = ((size_t)(bh * NPART + part)) * CG + qslot;
      pm[o] = m;
      pl[o] = ls;
    }
    unsigned short* po =
        pctx + (((size_t)(bh * NPART + part)) * CG + qt * 32) * CD;
#pragma unroll
    for (int r = 0; r < 16; ++r) {
      const int qr2 = (r & 3) + 8 * (r >> 2) + 4 * hi;
      po[(size_t)qr2 * CD + ql] = f2bf(oc0[r]);
      po[(size_t)qr2 * CD + 32 + ql] = f2bf(oc1[r]);
    }
  }
}

// ---------------------------------------------------------------------------
__global__ __launch_bounds__(64) void k_combine(
    const float* __restrict__ pm, const float* __restrict__ pl,
    const unsigned short* __restrict__ pctx,
    const int* __restrict__ gpos, const int* __restrict__ gcount,
    float* __restrict__ ctx) {
  const int g = blockIdx.x;
  const int bh = blockIdx.y;
  const int b = bh / CH;
  if (g >= gcount[b]) return;
  const int d = threadIdx.x;
  float m = -1e30f;
  for (int c = 0; c < NPART; ++c)
    m = fmaxf(m, pm[((size_t)(bh * NPART + c)) * CG + g]);
  float L = 0.f, acc = 0.f;
  for (int c = 0; c < NPART; ++c) {
    const size_t o = ((size_t)(bh * NPART + c)) * CG + g;
    const float w = __expf(pm[o] - m);
    L = fmaf(w, pl[o], L);
    const float x = __uint_as_float((unsigned)pctx[o * CD + d] << 16);
    acc = fmaf(w, x, acc);
  }
  const int tok = gpos[b * CG + g];
  ctx[((size_t)(bh * CS + tok)) * CD + d] = acc / L;
}

extern "C" void kernel_launch(void* const* d_in, const int* in_sizes, int n_in,
                              void* d_out, int out_size, void* d_ws, size_t ws_size,
                              hipStream_t stream) {
  const float* q = (const float*)d_in[0];
  const float* k = (const float*)d_in[1];
  const float* v = (const float*)d_in[2];
  const int* mask = (const int*)d_in[3];

  float* ctx = (float*)d_out;
  float* probs = ctx + (size_t)CBH * CS * CD;

  char* ws = (char*)d_ws;
  int* gpos = (int*)ws;                                  // 512 B
  int* gcount = (int*)(ws + 512);                        // 512 B
  float* pm = (float*)(ws + 1024);                       // CBH*NPART*CG f32
  float* pl = pm + (size_t)CBH * NPART * CG;             // CBH*NPART*CG f32
  unsigned short* pctx =
      (unsigned short*)(pl + (size_t)CBH * NPART * CG);  // CBH*NPART*CG*CD bf16

  k_setup<<<dim3(CB), dim3(64), 0, stream>>>(mask, gpos, gcount);
  k_main<<<dim3(NW1 + G2NCH, CBH), dim3(256), 0, stream>>>(
      q, k, v, gpos, gcount, ctx, probs, pm, pl, pctx);
  k_combine<<<dim3(CG, CBH), dim3(64), 0, stream>>>(
      pm, pl, pctx, gpos, gcount, ctx);
}